// Round 2
// baseline (879.873 us; speedup 1.0000x reference)
//
#include <hip/hip_runtime.h>

// SelfAttention block (VAE-style AttnBlock), fp32 baseline. (Round-1 resubmit:
// round-0 bench died on container acquisition, not on the kernel.)
// x:[8,512,32,32] -> GN(32,affine) -> qkv GEMM -> 8-head attention (t=1024,ch=64)
// -> proj GEMM + 1/sqrt(2)*xn residual -> GN(32, no affine).
//
// ws layout: [xn: 8*512*1024 f32 = 16.8MB][qkv: 8*1536*1024 f32 = 50.3MB] = 67MB.
// attention writes its output over the q-region of qkv (each block reads only its
// own q columns before writing them). proj writes y into d_out; gn2 runs in-place.

constexpr int NB  = 8;
constexpr int NC  = 512;
constexpr int NT  = 1024;
constexpr int CPG = 16;    // channels per group (512/32)
constexpr int NH  = 8;
constexpr int M3  = 1536;

#define EPSV      1e-5f
#define RES_SCALE 0.7071067811865476f
#define QK_SCALE  0.35355339059327376f   // 64^-0.25, folded into q and k rows

// ---------------------------------------------------------------- GroupNorm
template<bool AFFINE>
__global__ __launch_bounds__(256) void groupnorm_kernel(
    const float* __restrict__ src0, const float* __restrict__ gw,
    const float* __restrict__ gb, float* __restrict__ dst0)
{
  const int tid = threadIdx.x;
  const int b = blockIdx.x >> 5;
  const int g = blockIdx.x & 31;
  const size_t off = ((size_t)(b * NC + g * CPG)) * NT;   // group data contiguous
  const float* src = src0 + off;
  float* dst = dst0 + off;

  const float4* s4 = (const float4*)src;
  float sum = 0.f, sq = 0.f;
  #pragma unroll 4
  for (int i = tid; i < CPG * NT / 4; i += 256) {
    float4 v = s4[i];
    sum += v.x + v.y + v.z + v.w;
    sq  += v.x * v.x + v.y * v.y + v.z * v.z + v.w * v.w;
  }
  #pragma unroll
  for (int off2 = 32; off2; off2 >>= 1) {
    sum += __shfl_xor(sum, off2);
    sq  += __shfl_xor(sq,  off2);
  }
  __shared__ float rs[4], rq[4], stats[2];
  const int wave = tid >> 6, lane = tid & 63;
  if (lane == 0) { rs[wave] = sum; rq[wave] = sq; }
  __syncthreads();
  if (tid == 0) {
    float S = rs[0] + rs[1] + rs[2] + rs[3];
    float Q = rq[0] + rq[1] + rq[2] + rq[3];
    float mean = S * (1.0f / (CPG * NT));
    float var  = Q * (1.0f / (CPG * NT)) - mean * mean;   // biased var (matches ref)
    stats[0] = mean;
    stats[1] = rsqrtf(var + EPSV);
  }
  __syncthreads();
  const float mean = stats[0], rstd = stats[1];
  float4* d4 = (float4*)dst;
  #pragma unroll 4
  for (int i = tid; i < CPG * NT / 4; i += 256) {
    float a, c2;
    if (AFFINE) {
      int ch = g * CPG + (i >> 8);      // 256 float4 per channel
      float wv = gw[ch];
      a  = rstd * wv;
      c2 = gb[ch] - mean * a;
    } else {
      a  = rstd;
      c2 = -mean * rstd;
    }
    float4 v = s4[i];
    v.x = v.x * a + c2; v.y = v.y * a + c2;
    v.z = v.z * a + c2; v.w = v.w * a + c2;
    d4[i] = v;
  }
}

// ---------------------------------------------------------------- GEMM
// MODE 0: qkv = (qkv_w @ xn + qkv_b) * row_scale -> qkvbuf (plain [b][1536][1024])
// MODE 1: y = proj_w @ a + proj_b + RES_SCALE*xn -> yout; a read from q-region of qkvbuf
template<int MODE>
__global__ __launch_bounds__(256) void gemm_kernel(
    const float* __restrict__ W, const float* __restrict__ bias,
    const float* __restrict__ xn, float* __restrict__ qkvbuf,
    float* __restrict__ yout)
{
  constexpr int BK = 16;
  __shared__ __attribute__((aligned(16))) float As[BK][128];   // [k][m] transposed
  __shared__ __attribute__((aligned(16))) float Bs[BK][132];   // [k][n], padded
  const int tid = threadIdx.x;
  const int bn = blockIdx.x, bm = blockIdx.y, b = blockIdx.z;
  const int tx = tid & 15, ty = tid >> 4;
  const int arow = tid >> 1, acol = (tid & 1) * 8;
  const int brow = tid >> 4, bcol = (tid & 15) * 8;
  const int n0 = bn * 128;

  float acc[8][8] = {};
  const float* Arow = W + (size_t)(bm * 128 + arow) * 512 + acol;

  for (int k0 = 0; k0 < 512; k0 += BK) {
    float4 a0 = *(const float4*)(Arow + k0);
    float4 a1 = *(const float4*)(Arow + k0 + 4);
    const int kk = k0 + brow;
    const float* bp;
    if (MODE == 0)
      bp = xn + ((size_t)b * NC + kk) * NT + n0 + bcol;
    else
      bp = qkvbuf + ((size_t)((b * NH + (kk >> 6)) * 192 + (kk & 63))) * NT + n0 + bcol;
    float4 b0 = *(const float4*)bp;
    float4 b1 = *(const float4*)(bp + 4);
    __syncthreads();
    As[acol + 0][arow] = a0.x; As[acol + 1][arow] = a0.y;
    As[acol + 2][arow] = a0.z; As[acol + 3][arow] = a0.w;
    As[acol + 4][arow] = a1.x; As[acol + 5][arow] = a1.y;
    As[acol + 6][arow] = a1.z; As[acol + 7][arow] = a1.w;
    *(float4*)&Bs[brow][bcol]     = b0;
    *(float4*)&Bs[brow][bcol + 4] = b1;
    __syncthreads();
    #pragma unroll
    for (int k = 0; k < BK; k++) {
      float4 ra0 = *(const float4*)&As[k][ty * 8];
      float4 ra1 = *(const float4*)&As[k][ty * 8 + 4];
      float4 rb0 = *(const float4*)&Bs[k][tx * 8];
      float4 rb1 = *(const float4*)&Bs[k][tx * 8 + 4];
      float ra[8] = {ra0.x, ra0.y, ra0.z, ra0.w, ra1.x, ra1.y, ra1.z, ra1.w};
      float rb[8] = {rb0.x, rb0.y, rb0.z, rb0.w, rb1.x, rb1.y, rb1.z, rb1.w};
      #pragma unroll
      for (int i = 0; i < 8; i++)
        #pragma unroll
        for (int j = 0; j < 8; j++)
          acc[i][j] = fmaf(ra[i], rb[j], acc[i][j]);
    }
  }

  if (MODE == 0) {
    #pragma unroll
    for (int i = 0; i < 8; i++) {
      const int m = bm * 128 + ty * 8 + i;
      const float scl = ((m % 192) < 128) ? QK_SCALE : 1.0f;  // q,k rows scaled
      const float bv = bias[m];
      float* orow = qkvbuf + ((size_t)b * M3 + m) * NT + n0 + tx * 8;
      *(float4*)&orow[0] = make_float4((acc[i][0] + bv) * scl, (acc[i][1] + bv) * scl,
                                       (acc[i][2] + bv) * scl, (acc[i][3] + bv) * scl);
      *(float4*)&orow[4] = make_float4((acc[i][4] + bv) * scl, (acc[i][5] + bv) * scl,
                                       (acc[i][6] + bv) * scl, (acc[i][7] + bv) * scl);
    }
  } else {
    #pragma unroll
    for (int i = 0; i < 8; i++) {
      const int m = bm * 128 + ty * 8 + i;
      const float bv = bias[m];
      const float* xr = xn + ((size_t)b * NC + m) * NT + n0 + tx * 8;
      float* yr = yout + ((size_t)b * NC + m) * NT + n0 + tx * 8;
      float4 x0 = *(const float4*)&xr[0];
      float4 x1 = *(const float4*)&xr[4];
      *(float4*)&yr[0] = make_float4(acc[i][0] + bv + RES_SCALE * x0.x,
                                     acc[i][1] + bv + RES_SCALE * x0.y,
                                     acc[i][2] + bv + RES_SCALE * x0.z,
                                     acc[i][3] + bv + RES_SCALE * x0.w);
      *(float4*)&yr[4] = make_float4(acc[i][4] + bv + RES_SCALE * x1.x,
                                     acc[i][5] + bv + RES_SCALE * x1.y,
                                     acc[i][6] + bv + RES_SCALE * x1.z,
                                     acc[i][7] + bv + RES_SCALE * x1.w);
    }
  }
}

// ---------------------------------------------------------------- Attention
// qkvbuf viewed as [64 bh][192][1024]; rows 0-63=q,64-127=k,128-191=v (q,k pre-scaled).
// Block = (bh, 8 q-positions). Output a overwrites the q rows at its own t columns.
__global__ __launch_bounds__(256) void attn_kernel(float* __restrict__ qkvbuf)
{
  __shared__ __attribute__((aligned(16))) float S[8][1024];
  __shared__ float qs[64][8];
  __shared__ float Vs[64][65];   // [s_local][c], padded
  const int tid = threadIdx.x;
  const int bh = blockIdx.y;
  const int t0 = blockIdx.x * 8;
  float* base = qkvbuf + (size_t)bh * 192 * NT;
  const float* Kp = base + 64 * NT;
  const float* Vp = base + 128 * NT;

  for (int x = tid; x < 512; x += 256) {
    int c = x >> 3, i = x & 7;
    qs[c][i] = base[c * NT + t0 + i];
  }
  __syncthreads();

  // scores: thread owns s = tid + 256*j (j<4), all 8 rows
  float sc[4][8];
  #pragma unroll
  for (int j = 0; j < 4; j++)
    #pragma unroll
    for (int i = 0; i < 8; i++) sc[j][i] = 0.f;
  #pragma unroll 4
  for (int c = 0; c < 64; c++) {
    float kv[4];
    #pragma unroll
    for (int j = 0; j < 4; j++) kv[j] = Kp[c * NT + tid + 256 * j];
    #pragma unroll
    for (int i = 0; i < 8; i++) {
      float qv = qs[c][i];
      #pragma unroll
      for (int j = 0; j < 4; j++) sc[j][i] = fmaf(kv[j], qv, sc[j][i]);
    }
  }
  #pragma unroll
  for (int j = 0; j < 4; j++)
    #pragma unroll
    for (int i = 0; i < 8; i++)
      S[i][tid + 256 * j] = sc[j][i];
  __syncthreads();

  // softmax: wave w handles rows {w, w+4}
  const int wave = tid >> 6, lane = tid & 63;
  #pragma unroll
  for (int r = 0; r < 2; r++) {
    const int i = wave + r * 4;
    float mx = -1e30f;
    #pragma unroll
    for (int k = 0; k < 16; k++) mx = fmaxf(mx, S[i][lane + 64 * k]);
    #pragma unroll
    for (int off = 32; off; off >>= 1) mx = fmaxf(mx, __shfl_xor(mx, off));
    float ev[16];
    float sum = 0.f;
    #pragma unroll
    for (int k = 0; k < 16; k++) {
      ev[k] = __expf(S[i][lane + 64 * k] - mx);
      sum += ev[k];
    }
    #pragma unroll
    for (int off = 32; off; off >>= 1) sum += __shfl_xor(sum, off);
    const float inv = 1.0f / sum;
    #pragma unroll
    for (int k = 0; k < 16; k++) S[i][lane + 64 * k] = ev[k] * inv;
  }
  __syncthreads();

  // PV: thread owns (c = tid&63, rows iw and iw+4); V staged 64 cols at a time
  float acc0 = 0.f, acc1 = 0.f;
  const int c = tid & 63;
  const int iw = tid >> 6;
  for (int st = 0; st < NT; st += 64) {
    #pragma unroll
    for (int jj = 0; jj < 4; jj++) {
      int f = tid + 256 * jj;           // flat float4 index over 64x64 tile
      int cp = f >> 4;
      int sl = (f & 15) * 4;
      float4 v4 = *(const float4*)(Vp + cp * NT + st + sl);
      Vs[sl + 0][cp] = v4.x; Vs[sl + 1][cp] = v4.y;
      Vs[sl + 2][cp] = v4.z; Vs[sl + 3][cp] = v4.w;
    }
    __syncthreads();
    #pragma unroll
    for (int s = 0; s < 64; s += 4) {
      float4 w0 = *(const float4*)&S[iw][st + s];
      float4 w1 = *(const float4*)&S[iw + 4][st + s];
      acc0 += w0.x * Vs[s][c] + w0.y * Vs[s + 1][c] + w0.z * Vs[s + 2][c] + w0.w * Vs[s + 3][c];
      acc1 += w1.x * Vs[s][c] + w1.y * Vs[s + 1][c] + w1.z * Vs[s + 2][c] + w1.w * Vs[s + 3][c];
    }
    __syncthreads();
  }
  base[c * NT + t0 + iw]     = acc0;   // a overwrites q-region (safe: own columns)
  base[c * NT + t0 + iw + 4] = acc1;
}

// ---------------------------------------------------------------- launch
extern "C" void kernel_launch(void* const* d_in, const int* in_sizes, int n_in,
                              void* d_out, int out_size, void* d_ws, size_t ws_size,
                              hipStream_t stream)
{
  const float* x      = (const float*)d_in[0];
  const float* gn_w   = (const float*)d_in[1];
  const float* gn_b   = (const float*)d_in[2];
  const float* qkv_w  = (const float*)d_in[3];
  const float* qkv_b  = (const float*)d_in[4];
  const float* proj_w = (const float*)d_in[5];
  const float* proj_b = (const float*)d_in[6];
  float* out = (float*)d_out;

  float* xn     = (float*)d_ws;                    //  4,194,304 f32
  float* qkvbuf = xn + (size_t)NB * NC * NT;       // 12,582,912 f32 (total 67MB)

  groupnorm_kernel<true><<<dim3(NB * 32), 256, 0, stream>>>(x, gn_w, gn_b, xn);
  gemm_kernel<0><<<dim3(8, 12, NB), 256, 0, stream>>>(qkv_w, qkv_b, xn, qkvbuf, nullptr);
  attn_kernel<<<dim3(128, 64), 256, 0, stream>>>(qkvbuf);
  gemm_kernel<1><<<dim3(8, 4, NB), 256, 0, stream>>>(proj_w, proj_b, xn, qkvbuf, out);
  groupnorm_kernel<false><<<dim3(NB * 32), 256, 0, stream>>>(out, nullptr, nullptr, out);
}

// Round 3
// 454.343 us; speedup vs baseline: 1.9366x; 1.9366x over previous
//
#include <hip/hip_runtime.h>

// SelfAttention block. Round 2: attention rewritten as bf16-MFMA flash kernel.
// GN / GEMM kernels unchanged from the fp32 baseline (they total ~235us; attn was 645us).
//
// ws layout: [xn: 16.8MB][qkv: 50.3MB]. attn writes output over the q-region.

constexpr int NB  = 8;
constexpr int NC  = 512;
constexpr int NT  = 1024;
constexpr int CPG = 16;
constexpr int NH  = 8;
constexpr int M3  = 1536;

#define EPSV      1e-5f
#define RES_SCALE 0.7071067811865476f
#define QK_SCALE  0.35355339059327376f   // 64^-0.25, folded into q and k rows

typedef __attribute__((ext_vector_type(8))) short short8v;
typedef __attribute__((ext_vector_type(4))) float float4v;

// fp32 -> bf16 with round-to-nearest-even
static __device__ __forceinline__ unsigned short f2bf(float f) {
  unsigned int u = __builtin_bit_cast(unsigned int, f);
  u = (u + 0x7fffu + ((u >> 16) & 1u)) >> 16;
  return (unsigned short)u;
}

// ---------------------------------------------------------------- GroupNorm
template<bool AFFINE>
__global__ __launch_bounds__(256) void groupnorm_kernel(
    const float* __restrict__ src0, const float* __restrict__ gw,
    const float* __restrict__ gb, float* __restrict__ dst0)
{
  const int tid = threadIdx.x;
  const int b = blockIdx.x >> 5;
  const int g = blockIdx.x & 31;
  const size_t off = ((size_t)(b * NC + g * CPG)) * NT;
  const float* src = src0 + off;
  float* dst = dst0 + off;

  const float4* s4 = (const float4*)src;
  float sum = 0.f, sq = 0.f;
  #pragma unroll 4
  for (int i = tid; i < CPG * NT / 4; i += 256) {
    float4 v = s4[i];
    sum += v.x + v.y + v.z + v.w;
    sq  += v.x * v.x + v.y * v.y + v.z * v.z + v.w * v.w;
  }
  #pragma unroll
  for (int off2 = 32; off2; off2 >>= 1) {
    sum += __shfl_xor(sum, off2);
    sq  += __shfl_xor(sq,  off2);
  }
  __shared__ float rs[4], rq[4], stats[2];
  const int wave = tid >> 6, lane = tid & 63;
  if (lane == 0) { rs[wave] = sum; rq[wave] = sq; }
  __syncthreads();
  if (tid == 0) {
    float S = rs[0] + rs[1] + rs[2] + rs[3];
    float Q = rq[0] + rq[1] + rq[2] + rq[3];
    float mean = S * (1.0f / (CPG * NT));
    float var  = Q * (1.0f / (CPG * NT)) - mean * mean;
    stats[0] = mean;
    stats[1] = rsqrtf(var + EPSV);
  }
  __syncthreads();
  const float mean = stats[0], rstd = stats[1];
  float4* d4 = (float4*)dst;
  #pragma unroll 4
  for (int i = tid; i < CPG * NT / 4; i += 256) {
    float a, c2;
    if (AFFINE) {
      int ch = g * CPG + (i >> 8);
      float wv = gw[ch];
      a  = rstd * wv;
      c2 = gb[ch] - mean * a;
    } else {
      a  = rstd;
      c2 = -mean * rstd;
    }
    float4 v = s4[i];
    v.x = v.x * a + c2; v.y = v.y * a + c2;
    v.z = v.z * a + c2; v.w = v.w * a + c2;
    d4[i] = v;
  }
}

// ---------------------------------------------------------------- GEMM (fp32, unchanged)
template<int MODE>
__global__ __launch_bounds__(256) void gemm_kernel(
    const float* __restrict__ W, const float* __restrict__ bias,
    const float* __restrict__ xn, float* __restrict__ qkvbuf,
    float* __restrict__ yout)
{
  constexpr int BK = 16;
  __shared__ __attribute__((aligned(16))) float As[BK][128];
  __shared__ __attribute__((aligned(16))) float Bs[BK][132];
  const int tid = threadIdx.x;
  const int bn = blockIdx.x, bm = blockIdx.y, b = blockIdx.z;
  const int tx = tid & 15, ty = tid >> 4;
  const int arow = tid >> 1, acol = (tid & 1) * 8;
  const int brow = tid >> 4, bcol = (tid & 15) * 8;
  const int n0 = bn * 128;

  float acc[8][8] = {};
  const float* Arow = W + (size_t)(bm * 128 + arow) * 512 + acol;

  for (int k0 = 0; k0 < 512; k0 += BK) {
    float4 a0 = *(const float4*)(Arow + k0);
    float4 a1 = *(const float4*)(Arow + k0 + 4);
    const int kk = k0 + brow;
    const float* bp;
    if (MODE == 0)
      bp = xn + ((size_t)b * NC + kk) * NT + n0 + bcol;
    else
      bp = qkvbuf + ((size_t)((b * NH + (kk >> 6)) * 192 + (kk & 63))) * NT + n0 + bcol;
    float4 b0 = *(const float4*)bp;
    float4 b1 = *(const float4*)(bp + 4);
    __syncthreads();
    As[acol + 0][arow] = a0.x; As[acol + 1][arow] = a0.y;
    As[acol + 2][arow] = a0.z; As[acol + 3][arow] = a0.w;
    As[acol + 4][arow] = a1.x; As[acol + 5][arow] = a1.y;
    As[acol + 6][arow] = a1.z; As[acol + 7][arow] = a1.w;
    *(float4*)&Bs[brow][bcol]     = b0;
    *(float4*)&Bs[brow][bcol + 4] = b1;
    __syncthreads();
    #pragma unroll
    for (int k = 0; k < BK; k++) {
      float4 ra0 = *(const float4*)&As[k][ty * 8];
      float4 ra1 = *(const float4*)&As[k][ty * 8 + 4];
      float4 rb0 = *(const float4*)&Bs[k][tx * 8];
      float4 rb1 = *(const float4*)&Bs[k][tx * 8 + 4];
      float ra[8] = {ra0.x, ra0.y, ra0.z, ra0.w, ra1.x, ra1.y, ra1.z, ra1.w};
      float rb[8] = {rb0.x, rb0.y, rb0.z, rb0.w, rb1.x, rb1.y, rb1.z, rb1.w};
      #pragma unroll
      for (int i = 0; i < 8; i++)
        #pragma unroll
        for (int j = 0; j < 8; j++)
          acc[i][j] = fmaf(ra[i], rb[j], acc[i][j]);
    }
  }

  if (MODE == 0) {
    #pragma unroll
    for (int i = 0; i < 8; i++) {
      const int m = bm * 128 + ty * 8 + i;
      const float scl = ((m % 192) < 128) ? QK_SCALE : 1.0f;
      const float bv = bias[m];
      float* orow = qkvbuf + ((size_t)b * M3 + m) * NT + n0 + tx * 8;
      *(float4*)&orow[0] = make_float4((acc[i][0] + bv) * scl, (acc[i][1] + bv) * scl,
                                       (acc[i][2] + bv) * scl, (acc[i][3] + bv) * scl);
      *(float4*)&orow[4] = make_float4((acc[i][4] + bv) * scl, (acc[i][5] + bv) * scl,
                                       (acc[i][6] + bv) * scl, (acc[i][7] + bv) * scl);
    }
  } else {
    #pragma unroll
    for (int i = 0; i < 8; i++) {
      const int m = bm * 128 + ty * 8 + i;
      const float bv = bias[m];
      const float* xr = xn + ((size_t)b * NC + m) * NT + n0 + tx * 8;
      float* yr = yout + ((size_t)b * NC + m) * NT + n0 + tx * 8;
      float4 x0 = *(const float4*)&xr[0];
      float4 x1 = *(const float4*)&xr[4];
      *(float4*)&yr[0] = make_float4(acc[i][0] + bv + RES_SCALE * x0.x,
                                     acc[i][1] + bv + RES_SCALE * x0.y,
                                     acc[i][2] + bv + RES_SCALE * x0.z,
                                     acc[i][3] + bv + RES_SCALE * x0.w);
      *(float4*)&yr[4] = make_float4(acc[i][4] + bv + RES_SCALE * x1.x,
                                     acc[i][5] + bv + RES_SCALE * x1.y,
                                     acc[i][6] + bv + RES_SCALE * x1.z,
                                     acc[i][7] + bv + RES_SCALE * x1.w);
    }
  }
}

// ---------------------------------------------------------------- Attention (bf16 MFMA flash)
// qkvbuf viewed as [64 bh][192][1024]; rows 0-63=q, 64-127=k, 128-191=v (q,k pre-scaled).
// Block = (bh, 64 q-rows). 4 waves x 16 q-rows. s-tiles of 128 with online softmax.
// LDS tiles bf16 with XOR swizzle (col ^= (row&7)<<3 in ushort units) so all
// ds_read_b128 fragment reads are <=2-way bank-conflicted.
//
// MFMA 16x16x32 lane maps: A: [m=l&15][k=(l>>4)*8+j]; B: [k=(l>>4)*8+j][n=l&15];
// D: [row=(l>>4)*4+reg][col=l&15]  (m89-verified C/D layout).

#define IQ(t,c) ((t)*64  + ((c) ^ (((t)&7)<<3)))
#define IK(s,c) ((s)*64  + ((c) ^ (((s)&7)<<3)))
#define IV(c,s) ((c)*128 + ((s) ^ (((c)&7)<<3)))
#define IP(t,s) ((t)*128 + ((s) ^ (((t)&7)<<3)))

__global__ __launch_bounds__(256) void attn_mfma_kernel(float* __restrict__ qkvbuf)
{
  __shared__ unsigned short Qs[64 * 64];
  __shared__ unsigned short Ks[128 * 64];
  __shared__ unsigned short Vs[64 * 128];
  __shared__ unsigned short Ps[64 * 128];

  const int tid = threadIdx.x;
  const int w  = tid >> 6;        // wave 0..3 -> q rows w*16..w*16+15
  const int l  = tid & 63;
  const int lr = l & 15;          // fragment row/col index
  const int lg = l >> 4;          // k-group 0..3
  const int bh = blockIdx.y;
  const int t0 = blockIdx.x * 64;

  float* base = qkvbuf + (size_t)bh * 192 * NT;
  const float* Kp = base + 64 * NT;
  const float* Vp = base + 128 * NT;

  // ---- stage Q tile [64t][64c] (transpose of global q[c][t]) ----
  #pragma unroll
  for (int i = 0; i < 4; i++) {
    int idx = tid + 256 * i;             // 1024 float4 loads
    int c = idx >> 4, t4 = (idx & 15) * 4;
    float4 v = *(const float4*)(base + (size_t)c * NT + t0 + t4);
    Qs[IQ(t4 + 0, c)] = f2bf(v.x);
    Qs[IQ(t4 + 1, c)] = f2bf(v.y);
    Qs[IQ(t4 + 2, c)] = f2bf(v.z);
    Qs[IQ(t4 + 3, c)] = f2bf(v.w);
  }
  __syncthreads();

  // Q A-fragments for this wave's 16 q-rows (reused across all s-tiles)
  const short8v qa0 = *(const short8v*)&Qs[IQ(w * 16 + lr, lg * 8)];
  const short8v qa1 = *(const short8v*)&Qs[IQ(w * 16 + lr, 32 + lg * 8)];

  float4v out[4];
  #pragma unroll
  for (int nc = 0; nc < 4; nc++) out[nc] = (float4v){0.f, 0.f, 0.f, 0.f};
  float m_run[4] = {-1e30f, -1e30f, -1e30f, -1e30f};
  float l_run[4] = {0.f, 0.f, 0.f, 0.f};

  for (int s0 = 0; s0 < NT; s0 += 128) {
    __syncthreads();   // previous iteration's K/V/P reads complete
    // ---- stage K [128s][64c] (transposed) and V [64c][128s] ----
    #pragma unroll
    for (int i = 0; i < 8; i++) {
      int idx = tid + 256 * i;           // 2048 float4 loads each
      int c = idx >> 5, s4 = (idx & 31) * 4;
      float4 kv = *(const float4*)(Kp + (size_t)c * NT + s0 + s4);
      Ks[IK(s4 + 0, c)] = f2bf(kv.x);
      Ks[IK(s4 + 1, c)] = f2bf(kv.y);
      Ks[IK(s4 + 2, c)] = f2bf(kv.z);
      Ks[IK(s4 + 3, c)] = f2bf(kv.w);
      float4 vv = *(const float4*)(Vp + (size_t)c * NT + s0 + s4);
      unsigned int lo_ = (unsigned int)f2bf(vv.x) | ((unsigned int)f2bf(vv.y) << 16);
      unsigned int hi_ = (unsigned int)f2bf(vv.z) | ((unsigned int)f2bf(vv.w) << 16);
      *(uint2*)&Vs[IV(c, s4)] = make_uint2(lo_, hi_);
    }
    __syncthreads();

    // ---- QK^T: S[t][s] tile, 8 n-subtiles of 16 ----
    float4v sacc[8];
    #pragma unroll
    for (int n = 0; n < 8; n++) sacc[n] = (float4v){0.f, 0.f, 0.f, 0.f};
    #pragma unroll
    for (int n = 0; n < 8; n++) {
      short8v kb0 = *(const short8v*)&Ks[IK(n * 16 + lr, lg * 8)];
      short8v kb1 = *(const short8v*)&Ks[IK(n * 16 + lr, 32 + lg * 8)];
      sacc[n] = __builtin_amdgcn_mfma_f32_16x16x32_bf16(qa0, kb0, sacc[n], 0, 0, 0);
      sacc[n] = __builtin_amdgcn_mfma_f32_16x16x32_bf16(qa1, kb1, sacc[n], 0, 0, 0);
    }

    // ---- online softmax; lane holds rows t=w*16+lg*4+r, cols s=n*16+lr ----
    float nm[4], sc[4], ps[4];
    #pragma unroll
    for (int r = 0; r < 4; r++) {
      float mx = sacc[0][r];
      #pragma unroll
      for (int n = 1; n < 8; n++) mx = fmaxf(mx, sacc[n][r]);
      mx = fmaxf(mx, __shfl_xor(mx, 1));
      mx = fmaxf(mx, __shfl_xor(mx, 2));
      mx = fmaxf(mx, __shfl_xor(mx, 4));
      mx = fmaxf(mx, __shfl_xor(mx, 8));
      nm[r] = fmaxf(m_run[r], mx);
      sc[r] = __expf(m_run[r] - nm[r]);
      m_run[r] = nm[r];
      ps[r] = 0.f;
    }
    #pragma unroll
    for (int n = 0; n < 8; n++) {
      #pragma unroll
      for (int r = 0; r < 4; r++) {
        float p = __expf(sacc[n][r] - nm[r]);
        ps[r] += p;
        Ps[IP(w * 16 + lg * 4 + r, n * 16 + lr)] = f2bf(p);
      }
    }
    #pragma unroll
    for (int r = 0; r < 4; r++) {
      ps[r] += __shfl_xor(ps[r], 1);
      ps[r] += __shfl_xor(ps[r], 2);
      ps[r] += __shfl_xor(ps[r], 4);
      ps[r] += __shfl_xor(ps[r], 8);
      l_run[r] = l_run[r] * sc[r] + ps[r];
    }
    #pragma unroll
    for (int nc = 0; nc < 4; nc++) {
      out[nc][0] *= sc[0]; out[nc][1] *= sc[1];
      out[nc][2] *= sc[2]; out[nc][3] *= sc[3];
    }

    // ---- PV: out[t][c] += P[t][s] * v[c][s]; P read is wave-local (no barrier) ----
    #pragma unroll
    for (int kc = 0; kc < 4; kc++) {
      short8v pa = *(const short8v*)&Ps[IP(w * 16 + lr, kc * 32 + lg * 8)];
      #pragma unroll
      for (int nc = 0; nc < 4; nc++) {
        short8v vb = *(const short8v*)&Vs[IV(nc * 16 + lr, kc * 32 + lg * 8)];
        out[nc] = __builtin_amdgcn_mfma_f32_16x16x32_bf16(pa, vb, out[nc], 0, 0, 0);
      }
    }
  }

  // ---- epilogue: divide by softmax denom, write a over the q-region ----
  float inv[4];
  #pragma unroll
  for (int r = 0; r < 4; r++) inv[r] = 1.0f / l_run[r];
  #pragma unroll
  for (int nc = 0; nc < 4; nc++) {
    #pragma unroll
    for (int r = 0; r < 4; r++) {
      int c = nc * 16 + lr;
      int t = t0 + w * 16 + lg * 4 + r;
      base[(size_t)c * NT + t] = out[nc][r] * inv[r];
    }
  }
}

// ---------------------------------------------------------------- launch
extern "C" void kernel_launch(void* const* d_in, const int* in_sizes, int n_in,
                              void* d_out, int out_size, void* d_ws, size_t ws_size,
                              hipStream_t stream)
{
  const float* x      = (const float*)d_in[0];
  const float* gn_w   = (const float*)d_in[1];
  const float* gn_b   = (const float*)d_in[2];
  const float* qkv_w  = (const float*)d_in[3];
  const float* qkv_b  = (const float*)d_in[4];
  const float* proj_w = (const float*)d_in[5];
  const float* proj_b = (const float*)d_in[6];
  float* out = (float*)d_out;

  float* xn     = (float*)d_ws;
  float* qkvbuf = xn + (size_t)NB * NC * NT;

  groupnorm_kernel<true><<<dim3(NB * 32), 256, 0, stream>>>(x, gn_w, gn_b, xn);
  gemm_kernel<0><<<dim3(8, 12, NB), 256, 0, stream>>>(qkv_w, qkv_b, xn, qkvbuf, nullptr);
  attn_mfma_kernel<<<dim3(16, 64), 256, 0, stream>>>(qkvbuf);
  gemm_kernel<1><<<dim3(8, 4, NB), 256, 0, stream>>>(proj_w, proj_b, xn, qkvbuf, out);
  groupnorm_kernel<false><<<dim3(NB * 32), 256, 0, stream>>>(out, nullptr, nullptr, out);
}

// Round 4
// 231.361 us; speedup vs baseline: 3.8030x; 1.9638x over previous
//
#include <hip/hip_runtime.h>

// SelfAttention block, round 4: all GEMMs + attention on bf16 MFMA.
// Dataflow (all MFMA operands k-contiguous in global -> linear LDS staging):
//   gn1: x -> xn_f32 [b][c][t]
//   transpose: xn_f32 -> xn_bt [b][t][c] bf16
//   convert: qkv_w/proj_w -> bf16
//   qkv GEMM: qk_t [b][t][h*128 + (q:0-63,k:64-127)] bf16 (scaled), v_nat [b][c][t] bf16
//   attn: qk_t/v_nat -> a_t [b][t][c] bf16
//   proj GEMM: + bias + RES_SCALE*xn_f32 -> d_out fp32; gn2 in-place.
// ws: xn_f32 16.8M | xn_bt 8.4M | qk_t 16.8M | v_nat 8.4M | a_t 8.4M | wb 2.1M = 60.8MB

typedef unsigned short u16;
typedef __attribute__((ext_vector_type(8))) short short8v;
typedef __attribute__((ext_vector_type(4))) float float4v;

constexpr int NB = 8, NC = 512, NT = 1024, CPG = 16;
#define EPSV 1e-5f
#define RES_SCALE 0.7071067811865476f
#define QK_SCALE 0.35355339059327376f

static __device__ __forceinline__ u16 f2bf(float f) {
  unsigned int u = __builtin_bit_cast(unsigned int, f);
  u = (u + 0x7fffu + ((u >> 16) & 1u)) >> 16;
  return (u16)u;
}

// ---------------------------------------------------------------- GroupNorm
template<bool AFFINE>
__global__ __launch_bounds__(256) void groupnorm_kernel(
    const float* __restrict__ src0, const float* __restrict__ gw,
    const float* __restrict__ gb, float* __restrict__ dst0)
{
  const int tid = threadIdx.x;
  const int b = blockIdx.x >> 5;
  const int g = blockIdx.x & 31;
  const size_t off = ((size_t)(b * NC + g * CPG)) * NT;
  const float* src = src0 + off;
  float* dst = dst0 + off;

  const float4* s4 = (const float4*)src;
  float sum = 0.f, sq = 0.f;
  #pragma unroll 4
  for (int i = tid; i < CPG * NT / 4; i += 256) {
    float4 v = s4[i];
    sum += v.x + v.y + v.z + v.w;
    sq  += v.x * v.x + v.y * v.y + v.z * v.z + v.w * v.w;
  }
  #pragma unroll
  for (int off2 = 32; off2; off2 >>= 1) {
    sum += __shfl_xor(sum, off2);
    sq  += __shfl_xor(sq,  off2);
  }
  __shared__ float rs[4], rq[4], stats[2];
  const int wave = tid >> 6, lane = tid & 63;
  if (lane == 0) { rs[wave] = sum; rq[wave] = sq; }
  __syncthreads();
  if (tid == 0) {
    float S = rs[0] + rs[1] + rs[2] + rs[3];
    float Q = rq[0] + rq[1] + rq[2] + rq[3];
    float mean = S * (1.0f / (CPG * NT));
    float var  = Q * (1.0f / (CPG * NT)) - mean * mean;
    stats[0] = mean;
    stats[1] = rsqrtf(var + EPSV);
  }
  __syncthreads();
  const float mean = stats[0], rstd = stats[1];
  float4* d4 = (float4*)dst;
  #pragma unroll 4
  for (int i = tid; i < CPG * NT / 4; i += 256) {
    float a, c2;
    if (AFFINE) {
      int ch = g * CPG + (i >> 8);
      float wv = gw[ch];
      a  = rstd * wv;
      c2 = gb[ch] - mean * a;
    } else {
      a  = rstd;
      c2 = -mean * rstd;
    }
    float4 v = s4[i];
    v.x = v.x * a + c2; v.y = v.y * a + c2;
    v.z = v.z * a + c2; v.w = v.w * a + c2;
    d4[i] = v;
  }
}

// ---------------------------------------------------------------- f32 -> bf16 convert
__global__ __launch_bounds__(256) void convert_bf16_kernel(
    const float* __restrict__ in, u16* __restrict__ out, int n8)
{
  const int i = blockIdx.x * 256 + threadIdx.x;
  if (i >= n8) return;
  const float4 a = *(const float4*)(in + (size_t)i * 8);
  const float4 b = *(const float4*)(in + (size_t)i * 8 + 4);
  short8v o;
  o[0] = (short)f2bf(a.x); o[1] = (short)f2bf(a.y);
  o[2] = (short)f2bf(a.z); o[3] = (short)f2bf(a.w);
  o[4] = (short)f2bf(b.x); o[5] = (short)f2bf(b.y);
  o[6] = (short)f2bf(b.z); o[7] = (short)f2bf(b.w);
  *(short8v*)(out + (size_t)i * 8) = o;
}

// ---------------------------------------------------------------- xn_f32 [c][t] -> xn_bt [t][c]
__global__ __launch_bounds__(256) void transpose_kernel(
    const float* __restrict__ xnf, u16* __restrict__ xbt)
{
  __shared__ __attribute__((aligned(16))) u16 T[64 * 80];
  const int tid = threadIdx.x;
  const int tt = blockIdx.x, cc = blockIdx.y, b = blockIdx.z;
  const int c = tid >> 2, tch = (tid & 3) * 16;
  const float* src = xnf + ((size_t)b * NC + cc * 64 + c) * NT + tt * 64 + tch;
  #pragma unroll
  for (int j = 0; j < 4; j++) {
    float4 v = *(const float4*)(src + j * 4);
    T[(tch + j * 4 + 0) * 80 + c] = f2bf(v.x);
    T[(tch + j * 4 + 1) * 80 + c] = f2bf(v.y);
    T[(tch + j * 4 + 2) * 80 + c] = f2bf(v.z);
    T[(tch + j * 4 + 3) * 80 + c] = f2bf(v.w);
  }
  __syncthreads();
  const int t = tid >> 2, cp = (tid & 3) * 2;
  u16* dst = xbt + ((size_t)b * NT + tt * 64 + t) * NC + cc * 64;
  #pragma unroll
  for (int q = 0; q < 2; q++)
    *(short8v*)(dst + (cp + q) * 8) = *(const short8v*)(T + t * 80 + (cp + q) * 8);
}

// ---------------------------------------------------------------- MFMA GEMM
// MODE 0: qkv = qkv_wb @ xn^T; q,k (scaled) -> qk_t [b][t][1024]; v -> v_nat [b][c][t]
// MODE 1: out = proj_wb @ a^T + bias + RES_SCALE*xn_f32 -> outF [b][c][t] fp32
// A-frag: [m=l&15][k=(l>>4)*8+j]; B-frag: [k=(l>>4)*8+j][n=l&15];
// D: [row(m)=(l>>4)*4+reg][col(n)=l&15]  (verified round 2/3).
template<int MODE>
__global__ __launch_bounds__(256) void mfma_gemm_kernel(
    const u16* __restrict__ Wb, const float* __restrict__ bias,
    const u16* __restrict__ Bt, u16* __restrict__ qkT,
    u16* __restrict__ vN, float* __restrict__ outF,
    const float* __restrict__ xnf)
{
  __shared__ __attribute__((aligned(16))) u16 lds[(MODE == 1) ? 17408 : 16384];
  u16* As = lds;          // [128 m][64 k], k-chunk XOR-swizzled
  u16* Bs = lds + 8192;   // [128 n][64 k], swizzled
  const int tid = threadIdx.x;
  const int w = tid >> 6, l = tid & 63, lr = l & 15, lg = l >> 4;
  const int wm = (w >> 1) * 64, wn = (w & 1) * 64;
  const int bn = blockIdx.x * 128, bm = blockIdx.y * 128, b = blockIdx.z;

  const u16* Ag = Wb + (size_t)bm * 512;
  const u16* Bg = Bt + ((size_t)b * NT + bn) * 512;
  const int sr = tid >> 3;   // staging row 0..31 (+32*j)
  const int sc = tid & 7;    // staging k-chunk

  float4v acc[4][4];
  #pragma unroll
  for (int i = 0; i < 4; i++)
    #pragma unroll
    for (int j = 0; j < 4; j++) acc[i][j] = (float4v){0.f, 0.f, 0.f, 0.f};

  for (int k0 = 0; k0 < 512; k0 += 64) {
    short8v av[4], bv[4];
    #pragma unroll
    for (int j = 0; j < 4; j++) {
      const int m = sr + 32 * j;
      av[j] = *(const short8v*)(Ag + (size_t)m * 512 + k0 + sc * 8);
      bv[j] = *(const short8v*)(Bg + (size_t)m * 512 + k0 + sc * 8);
    }
    __syncthreads();
    #pragma unroll
    for (int j = 0; j < 4; j++) {
      const int m = sr + 32 * j;
      *(short8v*)(As + m * 64 + ((sc ^ (m & 7)) * 8)) = av[j];
      *(short8v*)(Bs + m * 64 + ((sc ^ (m & 7)) * 8)) = bv[j];
    }
    __syncthreads();
    #pragma unroll
    for (int kk = 0; kk < 2; kk++) {
      short8v af[4], bf[4];
      #pragma unroll
      for (int mi = 0; mi < 4; mi++) {
        const int m = wm + mi * 16 + lr;
        af[mi] = *(const short8v*)(As + m * 64 + (((kk * 4 + lg) ^ (m & 7)) * 8));
      }
      #pragma unroll
      for (int ni = 0; ni < 4; ni++) {
        const int n = wn + ni * 16 + lr;
        bf[ni] = *(const short8v*)(Bs + n * 64 + (((kk * 4 + lg) ^ (n & 7)) * 8));
      }
      #pragma unroll
      for (int mi = 0; mi < 4; mi++)
        #pragma unroll
        for (int ni = 0; ni < 4; ni++)
          acc[mi][ni] = __builtin_amdgcn_mfma_f32_16x16x32_bf16(af[mi], bf[ni], acc[mi][ni], 0, 0, 0);
    }
  }

  if (MODE == 0) {
    #pragma unroll
    for (int mi = 0; mi < 4; mi++) {
      const int m0 = bm + wm + mi * 16 + lg * 4;   // 4 consecutive rows, one zone
      const int head = m0 / 192;
      const int r0 = m0 - head * 192;
      const float4 bv4 = *(const float4*)(bias + m0);
      if (r0 < 128) {                               // q or k: scaled, transposed store
        const int col = head * 128 + r0;
        #pragma unroll
        for (int ni = 0; ni < 4; ni++) {
          const int t = bn + wn + ni * 16 + lr;
          unsigned int lo = (unsigned)f2bf((acc[mi][ni][0] + bv4.x) * QK_SCALE) |
                            ((unsigned)f2bf((acc[mi][ni][1] + bv4.y) * QK_SCALE) << 16);
          unsigned int hi = (unsigned)f2bf((acc[mi][ni][2] + bv4.z) * QK_SCALE) |
                            ((unsigned)f2bf((acc[mi][ni][3] + bv4.w) * QK_SCALE) << 16);
          *(uint2*)(qkT + ((size_t)b * NT + t) * 1024 + col) = make_uint2(lo, hi);
        }
      } else {                                      // v: natural [c][t] store
        const int vc = head * 64 + (r0 - 128);
        #pragma unroll
        for (int ni = 0; ni < 4; ni++) {
          const int t = bn + wn + ni * 16 + lr;
          vN[((size_t)b * NC + vc + 0) * NT + t] = f2bf(acc[mi][ni][0] + bv4.x);
          vN[((size_t)b * NC + vc + 1) * NT + t] = f2bf(acc[mi][ni][1] + bv4.y);
          vN[((size_t)b * NC + vc + 2) * NT + t] = f2bf(acc[mi][ni][2] + bv4.z);
          vN[((size_t)b * NC + vc + 3) * NT + t] = f2bf(acc[mi][ni][3] + bv4.w);
        }
      }
    }
  } else {
    float* Cs = (float*)lds;   // [64][136] fp32
    for (int ph = 0; ph < 2; ph++) {
      __syncthreads();
      if ((w >> 1) == ph) {
        #pragma unroll
        for (int mi = 0; mi < 4; mi++)
          #pragma unroll
          for (int ni = 0; ni < 4; ni++) {
            const int rr = mi * 16 + lg * 4;
            const int cc2 = wn + ni * 16 + lr;
            #pragma unroll
            for (int r = 0; r < 4; r++)
              Cs[(rr + r) * 136 + cc2] = acc[mi][ni][r];
          }
      }
      __syncthreads();
      const int mloc = tid >> 2;
      const int m = bm + ph * 64 + mloc;
      const float bv = bias[m];
      const int cb = (tid & 3) * 32;
      const float* cr = Cs + mloc * 136 + cb;
      const float* xr = xnf + ((size_t)b * NC + m) * NT + bn + cb;
      float* yr = outF + ((size_t)b * NC + m) * NT + bn + cb;
      #pragma unroll
      for (int j = 0; j < 8; j++) {
        float4 c4 = *(const float4*)(cr + j * 4);
        float4 x4 = *(const float4*)(xr + j * 4);
        float4 o;
        o.x = c4.x + bv + RES_SCALE * x4.x;
        o.y = c4.y + bv + RES_SCALE * x4.y;
        o.z = c4.z + bv + RES_SCALE * x4.z;
        o.w = c4.w + bv + RES_SCALE * x4.w;
        *(float4*)(yr + j * 4) = o;
      }
    }
  }
}

// ---------------------------------------------------------------- Attention (bf16 MFMA flash)
#define IK(s,c) ((s)*64  + ((c) ^ (((s)&7)<<3)))
#define IVX(c,s) ((c)*128 + ((s) ^ (((c)&7)<<3)))
#define IP(t,s) ((t)*128 + ((s) ^ (((t)&7)<<3)))

__global__ __launch_bounds__(256) void attn_mfma_kernel(
    const u16* __restrict__ qkT, const u16* __restrict__ vN, u16* __restrict__ aT)
{
  __shared__ __attribute__((aligned(16))) u16 Ks[128 * 64];
  __shared__ __attribute__((aligned(16))) u16 Vs[64 * 128];
  __shared__ __attribute__((aligned(16))) u16 Ps[64 * 128];
  const int tid = threadIdx.x;
  const int w = tid >> 6, l = tid & 63, lr = l & 15, lg = l >> 4;
  const int bh = blockIdx.y;
  const int b = bh >> 3, h = bh & 7;
  const int t0 = blockIdx.x * 64;

  const u16* qbase = qkT + (size_t)b * NT * 1024 + h * 128;
  const u16* kbase = qbase + 64;
  const u16* vbase = vN + ((size_t)b * NC + h * 64) * NT;

  // Q A-frags straight from global (k-contiguous), reused for all s-tiles
  const size_t qrow = (size_t)(t0 + w * 16 + lr) * 1024;
  const short8v qa0 = *(const short8v*)(qbase + qrow + lg * 8);
  const short8v qa1 = *(const short8v*)(qbase + qrow + 32 + lg * 8);

  float4v out[4];
  #pragma unroll
  for (int nc = 0; nc < 4; nc++) out[nc] = (float4v){0.f, 0.f, 0.f, 0.f};
  float m_run[4] = {-1e30f, -1e30f, -1e30f, -1e30f};
  float l_run[4] = {0.f, 0.f, 0.f, 0.f};

  for (int s0 = 0; s0 < NT; s0 += 128) {
    __syncthreads();
    // K stage: [128 s][64 c] linear b128 copies (global k-contiguous)
    #pragma unroll
    for (int j = 0; j < 4; j++) {
      const int flat = tid + 256 * j;
      const int s = flat >> 3, cl = flat & 7;
      short8v kv = *(const short8v*)(kbase + (size_t)(s0 + s) * 1024 + cl * 8);
      *(short8v*)(Ks + s * 64 + ((cl ^ (s & 7)) * 8)) = kv;
    }
    // V stage: [64 c][128 s] linear b128 copies (v_nat s-contiguous)
    #pragma unroll
    for (int j = 0; j < 4; j++) {
      const int flat = tid + 256 * j;
      const int c = flat >> 4, scn = flat & 15;
      short8v vv = *(const short8v*)(vbase + (size_t)c * NT + s0 + scn * 8);
      *(short8v*)(Vs + c * 128 + ((scn ^ (c & 7)) * 8)) = vv;
    }
    __syncthreads();

    // QK^T
    float4v sacc[8];
    #pragma unroll
    for (int n = 0; n < 8; n++) sacc[n] = (float4v){0.f, 0.f, 0.f, 0.f};
    #pragma unroll
    for (int n = 0; n < 8; n++) {
      const int srow = n * 16 + lr;
      short8v kb0 = *(const short8v*)(Ks + srow * 64 + ((lg ^ (srow & 7)) * 8));
      short8v kb1 = *(const short8v*)(Ks + srow * 64 + (((4 + lg) ^ (srow & 7)) * 8));
      sacc[n] = __builtin_amdgcn_mfma_f32_16x16x32_bf16(qa0, kb0, sacc[n], 0, 0, 0);
      sacc[n] = __builtin_amdgcn_mfma_f32_16x16x32_bf16(qa1, kb1, sacc[n], 0, 0, 0);
    }

    // online softmax; lane: rows t = w*16+lg*4+r, cols s = n*16+lr
    float nm[4], sc4[4], ps[4];
    #pragma unroll
    for (int r = 0; r < 4; r++) {
      float mx = sacc[0][r];
      #pragma unroll
      for (int n = 1; n < 8; n++) mx = fmaxf(mx, sacc[n][r]);
      mx = fmaxf(mx, __shfl_xor(mx, 1));
      mx = fmaxf(mx, __shfl_xor(mx, 2));
      mx = fmaxf(mx, __shfl_xor(mx, 4));
      mx = fmaxf(mx, __shfl_xor(mx, 8));
      nm[r] = fmaxf(m_run[r], mx);
      sc4[r] = __expf(m_run[r] - nm[r]);
      m_run[r] = nm[r];
      ps[r] = 0.f;
    }
    #pragma unroll
    for (int n = 0; n < 8; n++) {
      #pragma unroll
      for (int r = 0; r < 4; r++) {
        float p = __expf(sacc[n][r] - nm[r]);
        ps[r] += p;
        Ps[IP(w * 16 + lg * 4 + r, n * 16 + lr)] = f2bf(p);
      }
    }
    #pragma unroll
    for (int r = 0; r < 4; r++) {
      ps[r] += __shfl_xor(ps[r], 1);
      ps[r] += __shfl_xor(ps[r], 2);
      ps[r] += __shfl_xor(ps[r], 4);
      ps[r] += __shfl_xor(ps[r], 8);
      l_run[r] = l_run[r] * sc4[r] + ps[r];
    }
    #pragma unroll
    for (int nc = 0; nc < 4; nc++) {
      out[nc][0] *= sc4[0]; out[nc][1] *= sc4[1];
      out[nc][2] *= sc4[2]; out[nc][3] *= sc4[3];
    }

    // PV (P read is wave-local; no extra barrier)
    #pragma unroll
    for (int kc = 0; kc < 4; kc++) {
      short8v pa = *(const short8v*)(Ps + IP(w * 16 + lr, kc * 32 + lg * 8));
      #pragma unroll
      for (int nc = 0; nc < 4; nc++) {
        const int crow = nc * 16 + lr;
        short8v vb = *(const short8v*)(Vs + crow * 128 + (((kc * 4 + lg) ^ (crow & 7)) * 8));
        out[nc] = __builtin_amdgcn_mfma_f32_16x16x32_bf16(pa, vb, out[nc], 0, 0, 0);
      }
    }
  }

  // epilogue: LDS-routed coalesced bf16 store to a_t[b][t][c]
  __syncthreads();
  u16* At = Ps;   // [64][80]
  float inv[4];
  #pragma unroll
  for (int r = 0; r < 4; r++) inv[r] = 1.0f / l_run[r];
  #pragma unroll
  for (int nc = 0; nc < 4; nc++)
    #pragma unroll
    for (int r = 0; r < 4; r++)
      At[(w * 16 + lg * 4 + r) * 80 + nc * 16 + lr] = f2bf(out[nc][r] * inv[r]);
  __syncthreads();
  const int t = tid >> 2, cp = (tid & 3) * 2;
  u16* dst = aT + ((size_t)b * NT + t0 + t) * NC + h * 64;
  #pragma unroll
  for (int q = 0; q < 2; q++)
    *(short8v*)(dst + (cp + q) * 8) = *(const short8v*)(At + t * 80 + (cp + q) * 8);
}

// ---------------------------------------------------------------- launch
extern "C" void kernel_launch(void* const* d_in, const int* in_sizes, int n_in,
                              void* d_out, int out_size, void* d_ws, size_t ws_size,
                              hipStream_t stream)
{
  const float* x      = (const float*)d_in[0];
  const float* gn_w   = (const float*)d_in[1];
  const float* gn_b   = (const float*)d_in[2];
  const float* qkv_w  = (const float*)d_in[3];
  const float* qkv_b  = (const float*)d_in[4];
  const float* proj_w = (const float*)d_in[5];
  const float* proj_b = (const float*)d_in[6];
  float* out = (float*)d_out;

  float* xn  = (float*)d_ws;                            // 4,194,304 f32
  u16* base16 = (u16*)(xn + (size_t)NB * NC * NT);
  u16* xbt = base16;                                    // 4,194,304 u16
  u16* qkT = xbt + (size_t)NB * NT * NC;                // 8,388,608 u16
  u16* vN  = qkT + (size_t)NB * NT * 1024;              // 4,194,304 u16
  u16* aT  = vN + (size_t)NB * NC * NT;                 // 4,194,304 u16
  u16* qwb = aT + (size_t)NB * NT * NC;                 //   786,432 u16
  u16* pwb = qwb + 1536 * 512;                          //   262,144 u16

  groupnorm_kernel<true><<<dim3(NB * 32), 256, 0, stream>>>(x, gn_w, gn_b, xn);
  convert_bf16_kernel<<<dim3(384), 256, 0, stream>>>(qkv_w, qwb, 98304);
  convert_bf16_kernel<<<dim3(128), 256, 0, stream>>>(proj_w, pwb, 32768);
  transpose_kernel<<<dim3(16, 8, NB), 256, 0, stream>>>(xn, xbt);
  mfma_gemm_kernel<0><<<dim3(8, 12, NB), 256, 0, stream>>>(qwb, qkv_b, xbt, qkT, vN, nullptr, nullptr);
  attn_mfma_kernel<<<dim3(16, 64), 256, 0, stream>>>(qkT, vN, aT);
  mfma_gemm_kernel<1><<<dim3(8, 4, NB), 256, 0, stream>>>(pwb, proj_b, aT, nullptr, nullptr, out, xn);
  groupnorm_kernel<false><<<dim3(NB * 32), 256, 0, stream>>>(out, nullptr, nullptr, out);
}